// Round 1
// baseline (267.567 us; speedup 1.0000x reference)
//
#include <hip/hip_runtime.h>
#include <stdint.h>

#define NB 2
#define NT 4096
#define NC 768
#define NH 12
#define ND 64
#define NBT (NB*NT)      // 8192
#define NQKV (3*NC)      // 2304

typedef _Float16 half_t;
typedef __attribute__((ext_vector_type(8))) _Float16 f16x8;
typedef __attribute__((ext_vector_type(4))) _Float16 f16x4;
typedef __attribute__((ext_vector_type(2))) __fp16 fp16x2;   // native type of cvt_pkrtz
typedef __attribute__((ext_vector_type(4))) float f32x4;

#define MFMA16(a,b,c) __builtin_amdgcn_mfma_f32_16x16x32_f16((a),(b),(c),0,0,0)

__device__ __forceinline__ void load_lds16(const void* g, void* l) {
    auto gp = reinterpret_cast<__attribute__((address_space(1))) char*>(reinterpret_cast<uintptr_t>(g));
    auto lp = reinterpret_cast<__attribute__((address_space(3))) char*>(reinterpret_cast<uintptr_t>(l));
    __builtin_amdgcn_global_load_lds(gp, lp, 16, 0, 0);
}

// ---------------- pack fp32 -> f16 (vectorized) ----------------
__global__ __launch_bounds__(256) void k_pack(const float* __restrict__ in, half_t* __restrict__ out, int n4) {
    int i = blockIdx.x * 256 + threadIdx.x;
    if (i >= n4) return;
    float4 f = reinterpret_cast<const float4*>(in)[i];
    f16x4 h;
    h[0] = (half_t)f.x; h[1] = (half_t)f.y; h[2] = (half_t)f.z; h[3] = (half_t)f.w;
    reinterpret_cast<f16x4*>(out)[i] = h;
}

// ---------------- pack + transpose: in[K][N] fp32 -> out[N][K] f16 ----------------
__global__ __launch_bounds__(256) void k_packT(const float* __restrict__ in, half_t* __restrict__ out, int N, int K) {
    int idx = blockIdx.x * 256 + threadIdx.x;
    if (idx >= N * K) return;
    int n = idx / K, k = idx - n * K;
    out[idx] = (half_t)in[(size_t)k * N + n];
}

// ---------------- GEMM: C[M][N] = A[M][K=768] * Bt[N][K=768]^T + bias ----------------
template<int OUTF32>
__global__ __launch_bounds__(256) void k_gemm(const half_t* __restrict__ A, const half_t* __restrict__ Bt,
                                              const float* __restrict__ bias, void* __restrict__ out, int N) {
    __shared__ half_t As[128 * 32];
    __shared__ half_t Bs[128 * 32];
    const int tid = threadIdx.x;
    const int lane = tid & 63, w = tid >> 6;
    const int m0 = blockIdx.x * 128, n0 = blockIdx.y * 128;
    const int wm = (w >> 1) * 64, wn = (w & 1) * 64;
    const int lr = lane & 15, lk = (lane >> 4) * 8;

    f32x4 acc[4][4];
#pragma unroll
    for (int a = 0; a < 4; ++a)
#pragma unroll
        for (int bq = 0; bq < 4; ++bq) acc[a][bq] = (f32x4){0.f, 0.f, 0.f, 0.f};

    const int c0 = tid, c1 = 256 + tid;
    const int ldsbase = (tid & ~63) * 16;   // wave-uniform byte base for global_load_lds

    for (int ks = 0; ks < 24; ++ks) {
        const int k0 = ks * 32;
        __syncthreads();
        load_lds16(A  + (size_t)(m0 + (c0 >> 2)) * NC + k0 + (c0 & 3) * 8, (char*)As + ldsbase);
        load_lds16(Bt + (size_t)(n0 + (c0 >> 2)) * NC + k0 + (c0 & 3) * 8, (char*)Bs + ldsbase);
        load_lds16(A  + (size_t)(m0 + (c1 >> 2)) * NC + k0 + (c1 & 3) * 8, (char*)As + 4096 + ldsbase);
        load_lds16(Bt + (size_t)(n0 + (c1 >> 2)) * NC + k0 + (c1 & 3) * 8, (char*)Bs + 4096 + ldsbase);
        __syncthreads();
        f16x8 af[4], bf[4];
#pragma unroll
        for (int mi = 0; mi < 4; ++mi)
            af[mi] = *reinterpret_cast<const f16x8*>(&As[(wm + mi * 16 + lr) * 32 + lk]);
#pragma unroll
        for (int ni = 0; ni < 4; ++ni)
            bf[ni] = *reinterpret_cast<const f16x8*>(&Bs[(wn + ni * 16 + lr) * 32 + lk]);
#pragma unroll
        for (int mi = 0; mi < 4; ++mi)
#pragma unroll
            for (int ni = 0; ni < 4; ++ni)
                acc[mi][ni] = MFMA16(af[mi], bf[ni], acc[mi][ni]);
    }

    const int rg = (lane >> 4) * 4;   // C/D layout: row=(lane>>4)*4+i, col=lane&15
#pragma unroll
    for (int ni = 0; ni < 4; ++ni) {
        const int gn = n0 + wn + ni * 16 + lr;
        const float bv = bias[gn];
#pragma unroll
        for (int mi = 0; mi < 4; ++mi)
#pragma unroll
            for (int i = 0; i < 4; ++i) {
                const size_t gm = (size_t)(m0 + wm + mi * 16 + rg + i);
                const float v = acc[mi][ni][i] + bv;
                if (OUTF32) reinterpret_cast<float*>(out)[gm * N + gn] = v;
                else        reinterpret_cast<half_t*>(out)[gm * N + gn] = (half_t)v;
            }
    }
}

// ---------------- V repack: qkv[.,1536+h*64+d] -> Vt[bh][d][t] (LDS tile transpose) ----------------
__global__ __launch_bounds__(256) void k_vt(const half_t* __restrict__ qkv, half_t* __restrict__ Vt) {
    __shared__ half_t tile[64][72];
    const int tid = threadIdx.x;
    const int t0 = blockIdx.x * 64, bh = blockIdx.y;
    const int b = bh / NH, h = bh - b * NH;
    {
        const int tl = tid >> 2, dc = (tid & 3) * 16;
        const half_t* src = qkv + (size_t)(b * NT + t0 + tl) * NQKV + 2 * NC + h * ND + dc;
        f16x8 v0 = *reinterpret_cast<const f16x8*>(src);
        f16x8 v1 = *reinterpret_cast<const f16x8*>(src + 8);
        *reinterpret_cast<f16x8*>(&tile[tl][dc]) = v0;
        *reinterpret_cast<f16x8*>(&tile[tl][dc + 8]) = v1;
    }
    __syncthreads();
    {
        const int d = tid >> 2, tc = (tid & 3) * 16;
        half_t* dst = Vt + ((size_t)bh * ND + d) * NT + t0 + tc;
        f16x8 o0, o1;
#pragma unroll
        for (int j = 0; j < 8; ++j) o0[j] = tile[tc + j][d];
#pragma unroll
        for (int j = 0; j < 8; ++j) o1[j] = tile[tc + 8 + j][d];
        *reinterpret_cast<f16x8*>(dst) = o0;
        *reinterpret_cast<f16x8*>(dst + 8) = o1;
    }
}

// ---------------- Flash attention v5: 8 waves/block, key-split wave pairs ----------------
// Wave w: qw = w&3 owns 32 q-rows (2 q-frags, full 2x MFMA reuse), kw = w>>2 owns one
// 32-key half of each 64-key tile (st in {2kw, 2kw+1}; PV ks = kw). Per-block-iter LDS
// traffic / MFMA count / exp2 count are unchanged vs the 4-wave version, but resident
// waves double (12 -> 24 per CU) to cover LDS + L2 latency (prev version: 26% occupancy,
// both pipes < 52% => latency-bound). Wave pairs reduce y/l once at the end through an
// LDS buffer overlaid on the K/V tiles (union, 34 KB).
struct __align__(16) AttnSmem {
    union {
        struct { half_t K[2][64 * 64]; half_t V[2][64 * 64]; } m;   // 32 KB main
        struct { float y[4][64][32]; float l[4][64][2]; } r;        // 34 KB epilogue
    };
};

__global__ __launch_bounds__(512, 6) void k_attn(const half_t* __restrict__ qkv, const half_t* __restrict__ Vt,
                                                 half_t* __restrict__ Y) {
    __shared__ AttnSmem sm;
    const int tid = threadIdx.x, lane = tid & 63, w = tid >> 6;
    const int qw = w & 3, kw = w >> 2;
    const int lr = lane & 15, g = lane >> 4;
    const int qt = blockIdx.x, bh = blockIdx.y;
    const int b = bh / NH, h = bh - b * NH;
    const half_t* Qp = qkv + (size_t)b * NT * NQKV + h * ND;        // q cols
    const half_t* Kp = Qp + NC;                                     // k cols
    const half_t* Vbase = Vt + (size_t)bh * ND * NT;                // V^T [d][t]
    const int q0 = qt * 128 + qw * 32;

    // staging geometry: 512 threads x 16B = 8KB = one full 64x64 f16 tile per instr
    const int sr = tid >> 3;                                   // row 0..63
    const int colh = ((tid & 7) << 3) ^ ((sr & 7) << 3);       // swizzled source col (halfs)
    const int wub = (tid & ~63) * 16;                          // wave-uniform LDS byte base

    // Q fragments (B-operand: col=lr=q), 2 q-frags x 2 d-halves, pre-scaled by 1/sqrt(D)*log2(e)
    f16x8 aq[2][2];
    const half_t cch = (half_t)(0.125f * 1.4426950408889634f);
#pragma unroll
    for (int qf = 0; qf < 2; ++qf)
#pragma unroll
        for (int dh = 0; dh < 2; ++dh) {
            aq[qf][dh] = *reinterpret_cast<const f16x8*>(&Qp[(size_t)(q0 + qf * 16 + lr) * NQKV + dh * 32 + g * 8]);
#pragma unroll
            for (int j = 0; j < 8; ++j) aq[qf][dh][j] = aq[qf][dh][j] * cch;
        }

    // swizzled K-read columns (b128): row = st*16+lr, chunk ^= (lr&7)
    const int swk = (lr & 7) << 3;
    const int cA = (g * 8) ^ swk;          // d-chunk 0
    const int cB = (32 + g * 8) ^ swk;     // d-chunk 1
    // swizzled V-read columns (b64 pairs) for this wave's key-half (ks = kw)
    const int psw = lr & 7;
    const int goff = (g & 1) << 2;
    const int vcol[2] = { (((g >> 1) + 4 * kw + 0) ^ psw) * 8 + goff,
                          (((g >> 1) + 4 * kw + 2) ^ psw) * 8 + goff };

    f32x4 y[2][4];
#pragma unroll
    for (int qf = 0; qf < 2; ++qf)
#pragma unroll
        for (int df = 0; df < 4; ++df) y[qf][df] = (f32x4){0.f, 0.f, 0.f, 0.f};
    float l_[2] = {0.f, 0.f};

    auto stage = [&](int buf, const half_t* Ks, const half_t* Vs) {
        load_lds16(Ks, (char*)&sm.m.K[buf][0] + wub);
        load_lds16(Vs, (char*)&sm.m.V[buf][0] + wub);
    };

    const half_t* ksrc = Kp + (size_t)sr * NQKV + colh;
    const half_t* vsrc = Vbase + (size_t)sr * NT + colh;
    stage(0, ksrc, vsrc);
    ksrc += (size_t)64 * NQKV;
    vsrc += 64;
    __syncthreads();
    int cur = 0;
    const int stb = 2 * kw;

    for (int t = 0; t < NT / 64; ++t) {
        if (t < NT / 64 - 1) {
            stage(cur ^ 1, ksrc, vsrc);
            ksrc += (size_t)64 * NQKV;
            vsrc += 64;
        }

        // ---- QK^T (swapped), this wave's 32-key half: s[qf][sl][i] over st = stb+sl ----
        f32x4 s[2][2];
#pragma unroll
        for (int sl = 0; sl < 2; ++sl) { s[0][sl] = (f32x4){0.f,0.f,0.f,0.f}; s[1][sl] = (f32x4){0.f,0.f,0.f,0.f}; }
        const half_t* Kc = &sm.m.K[cur][0];
        __builtin_amdgcn_s_setprio(1);
#pragma unroll
        for (int sl = 0; sl < 2; ++sl) {
            const int row = (stb + sl) * 16 + lr;
            f16x8 bk0 = *reinterpret_cast<const f16x8*>(&Kc[row * 64 + cA]);
            s[0][sl] = MFMA16(bk0, aq[0][0], s[0][sl]);
            s[1][sl] = MFMA16(bk0, aq[1][0], s[1][sl]);
            f16x8 bk1 = *reinterpret_cast<const f16x8*>(&Kc[row * 64 + cB]);
            s[0][sl] = MFMA16(bk1, aq[0][1], s[0][sl]);
            s[1][sl] = MFMA16(bk1, aq[1][1], s[1][sl]);
        }
        __builtin_amdgcn_s_setprio(0);

        // ---- no-max softmax + lane-local pack: pb[qf] = packed p for this key-half ----
        f16x8 pb[2];
#pragma unroll
        for (int qf = 0; qf < 2; ++qf) {
            float ps = 0.f;
            union { f16x8 v; fp16x2 h[4]; } u;
#pragma unroll
            for (int hs = 0; hs < 2; ++hs) {   // hs: local st within this ks
                const float p0 = __builtin_amdgcn_exp2f(s[qf][hs][0]);
                const float p1 = __builtin_amdgcn_exp2f(s[qf][hs][1]);
                const float p2 = __builtin_amdgcn_exp2f(s[qf][hs][2]);
                const float p3 = __builtin_amdgcn_exp2f(s[qf][hs][3]);
                u.h[2 * hs]     = __builtin_amdgcn_cvt_pkrtz(p0, p1);
                u.h[2 * hs + 1] = __builtin_amdgcn_cvt_pkrtz(p2, p3);
                ps += (p0 + p1) + (p2 + p3);
            }
            pb[qf] = u.v;
            l_[qf] += ps;
        }

        // ---- PV (ks = kw): A = V^T rows, B = pb (register) ----
        const half_t* Vc = &sm.m.V[cur][0];
        __builtin_amdgcn_s_setprio(1);
#pragma unroll
        for (int df = 0; df < 4; ++df) {
            const half_t* vrow = &Vc[(df * 16 + lr) * 64];
            union { f16x8 v; f16x4 q[2]; } va;
            va.q[0] = *reinterpret_cast<const f16x4*>(vrow + vcol[0]);
            va.q[1] = *reinterpret_cast<const f16x4*>(vrow + vcol[1]);
            y[0][df] = MFMA16(va.v, pb[0], y[0][df]);
            y[1][df] = MFMA16(va.v, pb[1], y[1][df]);
        }
        __builtin_amdgcn_s_setprio(0);

        __syncthreads();   // drains stage vmcnt + all waves done reading buf[cur]
        cur ^= 1;
    }

    // ---- cross-wave (key-half) reduction: kw=1 publishes y/l, kw=0 combines+stores ----
    if (kw == 1) {
#pragma unroll
        for (int qf = 0; qf < 2; ++qf)
#pragma unroll
            for (int df = 0; df < 4; ++df) {
                const int jb = (qf * 16 + df * 4) ^ ((lane & 7) << 2);   // bank swizzle
                *reinterpret_cast<f32x4*>(&sm.r.y[qw][lane][jb]) = y[qf][df];
            }
        sm.r.l[qw][lane][0] = l_[0];
        sm.r.l[qw][lane][1] = l_[1];
    }
    __syncthreads();
    if (kw == 0) {
#pragma unroll
        for (int qf = 0; qf < 2; ++qf) {
#pragma unroll
            for (int df = 0; df < 4; ++df) {
                const int jb = (qf * 16 + df * 4) ^ ((lane & 7) << 2);
                const f32x4 yp = *reinterpret_cast<const f32x4*>(&sm.r.y[qw][lane][jb]);
                y[qf][df] += yp;
            }
            float l = l_[qf] + sm.r.l[qw][lane][qf];
            l += __shfl_xor(l, 16);
            l += __shfl_xor(l, 32);
            const float rl = 1.f / l;
            half_t* Yp = Y + (size_t)(b * NT + q0 + qf * 16 + lr) * NC + h * ND + g * 4;
#pragma unroll
            for (int df = 0; df < 4; ++df) {
                union { f16x4 v; fp16x2 hh[2]; } o;
                o.hh[0] = __builtin_amdgcn_cvt_pkrtz(y[qf][df][0] * rl, y[qf][df][1] * rl);
                o.hh[1] = __builtin_amdgcn_cvt_pkrtz(y[qf][df][2] * rl, y[qf][df][3] * rl);
                *reinterpret_cast<f16x4*>(Yp + df * 16) = o.v;
            }
        }
    }
}

extern "C" void kernel_launch(void* const* d_in, const int* in_sizes, int n_in,
                              void* d_out, int out_size, void* d_ws, size_t ws_size,
                              hipStream_t stream) {
    const float* x  = (const float*)d_in[0];
    const float* Wa = (const float*)d_in[1];
    const float* ba = (const float*)d_in[2];
    const float* Wp = (const float*)d_in[3];
    const float* bp = (const float*)d_in[4];
    float* out = (float*)d_out;

    char* ws = (char*)d_ws;
    half_t* xh   = (half_t*)ws; ws += (size_t)NBT * NC * 2;
    half_t* Wat  = (half_t*)ws; ws += (size_t)NQKV * NC * 2;
    half_t* Wpt  = (half_t*)ws; ws += (size_t)NC * NC * 2;
    half_t* qkvh = (half_t*)ws; ws += (size_t)NBT * NQKV * 2;
    half_t* vt   = (half_t*)ws; ws += (size_t)NB * NH * ND * NT * 2;
    half_t* yh   = (half_t*)ws; ws += (size_t)NBT * NC * 2;

    k_pack<<<(NBT * NC / 4 + 255) / 256, 256, 0, stream>>>(x, xh, NBT * NC / 4);
    k_packT<<<(NQKV * NC + 255) / 256, 256, 0, stream>>>(Wa, Wat, NQKV, NC);
    k_packT<<<(NC * NC + 255) / 256, 256, 0, stream>>>(Wp, Wpt, NC, NC);
    k_gemm<0><<<dim3(NBT / 128, NQKV / 128), 256, 0, stream>>>(xh, Wat, ba, qkvh, NQKV);
    k_vt<<<dim3(NT / 64, NB * NH), 256, 0, stream>>>(qkvh, vt);
    k_attn<<<dim3(NT / 128, NB * NH), 512, 0, stream>>>(qkvh, vt, yh);
    k_gemm<1><<<dim3(NBT / 128, NC / 128), 256, 0, stream>>>(yh, Wpt, bp, out, NC);
}

// Round 2
// 216.489 us; speedup vs baseline: 1.2359x; 1.2359x over previous
//
#include <hip/hip_runtime.h>
#include <stdint.h>

#define NB 2
#define NT 4096
#define NC 768
#define NH 12
#define ND 64
#define NBT (NB*NT)      // 8192
#define NQKV (3*NC)      // 2304

typedef _Float16 half_t;
typedef __attribute__((ext_vector_type(8))) _Float16 f16x8;
typedef __attribute__((ext_vector_type(4))) _Float16 f16x4;
typedef __attribute__((ext_vector_type(2))) __fp16 fp16x2;   // native type of cvt_pkrtz
typedef __attribute__((ext_vector_type(4))) float f32x4;

#define MFMA16(a,b,c) __builtin_amdgcn_mfma_f32_16x16x32_f16((a),(b),(c),0,0,0)

__device__ __forceinline__ void load_lds16(const void* g, void* l) {
    auto gp = reinterpret_cast<__attribute__((address_space(1))) char*>(reinterpret_cast<uintptr_t>(g));
    auto lp = reinterpret_cast<__attribute__((address_space(3))) char*>(reinterpret_cast<uintptr_t>(l));
    __builtin_amdgcn_global_load_lds(gp, lp, 16, 0, 0);
}

// ---------------- pack fp32 -> f16 (vectorized) ----------------
__global__ __launch_bounds__(256) void k_pack(const float* __restrict__ in, half_t* __restrict__ out, int n4) {
    int i = blockIdx.x * 256 + threadIdx.x;
    if (i >= n4) return;
    float4 f = reinterpret_cast<const float4*>(in)[i];
    f16x4 h;
    h[0] = (half_t)f.x; h[1] = (half_t)f.y; h[2] = (half_t)f.z; h[3] = (half_t)f.w;
    reinterpret_cast<f16x4*>(out)[i] = h;
}

// ---------------- pack + transpose: in[K][N] fp32 -> out[N][K] f16 ----------------
__global__ __launch_bounds__(256) void k_packT(const float* __restrict__ in, half_t* __restrict__ out, int N, int K) {
    int idx = blockIdx.x * 256 + threadIdx.x;
    if (idx >= N * K) return;
    int n = idx / K, k = idx - n * K;
    out[idx] = (half_t)in[(size_t)k * N + n];
}

// ---------------- GEMM: C[M][N] = A[M][K=768] * Bt[N][K=768]^T + bias ----------------
template<int OUTF32>
__global__ __launch_bounds__(256) void k_gemm(const half_t* __restrict__ A, const half_t* __restrict__ Bt,
                                              const float* __restrict__ bias, void* __restrict__ out, int N) {
    __shared__ half_t As[128 * 32];
    __shared__ half_t Bs[128 * 32];
    const int tid = threadIdx.x;
    const int lane = tid & 63, w = tid >> 6;
    const int m0 = blockIdx.x * 128, n0 = blockIdx.y * 128;
    const int wm = (w >> 1) * 64, wn = (w & 1) * 64;
    const int lr = lane & 15, lk = (lane >> 4) * 8;

    f32x4 acc[4][4];
#pragma unroll
    for (int a = 0; a < 4; ++a)
#pragma unroll
        for (int bq = 0; bq < 4; ++bq) acc[a][bq] = (f32x4){0.f, 0.f, 0.f, 0.f};

    const int c0 = tid, c1 = 256 + tid;
    const int ldsbase = (tid & ~63) * 16;   // wave-uniform byte base for global_load_lds

    for (int ks = 0; ks < 24; ++ks) {
        const int k0 = ks * 32;
        __syncthreads();
        load_lds16(A  + (size_t)(m0 + (c0 >> 2)) * NC + k0 + (c0 & 3) * 8, (char*)As + ldsbase);
        load_lds16(Bt + (size_t)(n0 + (c0 >> 2)) * NC + k0 + (c0 & 3) * 8, (char*)Bs + ldsbase);
        load_lds16(A  + (size_t)(m0 + (c1 >> 2)) * NC + k0 + (c1 & 3) * 8, (char*)As + 4096 + ldsbase);
        load_lds16(Bt + (size_t)(n0 + (c1 >> 2)) * NC + k0 + (c1 & 3) * 8, (char*)Bs + 4096 + ldsbase);
        __syncthreads();
        f16x8 af[4], bf[4];
#pragma unroll
        for (int mi = 0; mi < 4; ++mi)
            af[mi] = *reinterpret_cast<const f16x8*>(&As[(wm + mi * 16 + lr) * 32 + lk]);
#pragma unroll
        for (int ni = 0; ni < 4; ++ni)
            bf[ni] = *reinterpret_cast<const f16x8*>(&Bs[(wn + ni * 16 + lr) * 32 + lk]);
#pragma unroll
        for (int mi = 0; mi < 4; ++mi)
#pragma unroll
            for (int ni = 0; ni < 4; ++ni)
                acc[mi][ni] = MFMA16(af[mi], bf[ni], acc[mi][ni]);
    }

    const int rg = (lane >> 4) * 4;   // C/D layout: row=(lane>>4)*4+i, col=lane&15
#pragma unroll
    for (int ni = 0; ni < 4; ++ni) {
        const int gn = n0 + wn + ni * 16 + lr;
        const float bv = bias[gn];
#pragma unroll
        for (int mi = 0; mi < 4; ++mi)
#pragma unroll
            for (int i = 0; i < 4; ++i) {
                const size_t gm = (size_t)(m0 + wm + mi * 16 + rg + i);
                const float v = acc[mi][ni][i] + bv;
                if (OUTF32) reinterpret_cast<float*>(out)[gm * N + gn] = v;
                else        reinterpret_cast<half_t*>(out)[gm * N + gn] = (half_t)v;
            }
    }
}

// ---------------- V repack: qkv[.,1536+h*64+d] -> Vt[bh][d][t] (LDS tile transpose) ----------------
__global__ __launch_bounds__(256) void k_vt(const half_t* __restrict__ qkv, half_t* __restrict__ Vt) {
    __shared__ half_t tile[64][72];
    const int tid = threadIdx.x;
    const int t0 = blockIdx.x * 64, bh = blockIdx.y;
    const int b = bh / NH, h = bh - b * NH;
    {
        const int tl = tid >> 2, dc = (tid & 3) * 16;
        const half_t* src = qkv + (size_t)(b * NT + t0 + tl) * NQKV + 2 * NC + h * ND + dc;
        f16x8 v0 = *reinterpret_cast<const f16x8*>(src);
        f16x8 v1 = *reinterpret_cast<const f16x8*>(src + 8);
        *reinterpret_cast<f16x8*>(&tile[tl][dc]) = v0;
        *reinterpret_cast<f16x8*>(&tile[tl][dc + 8]) = v1;
    }
    __syncthreads();
    {
        const int d = tid >> 2, tc = (tid & 3) * 16;
        half_t* dst = Vt + ((size_t)bh * ND + d) * NT + t0 + tc;
        f16x8 o0, o1;
#pragma unroll
        for (int j = 0; j < 8; ++j) o0[j] = tile[tc + j][d];
#pragma unroll
        for (int j = 0; j < 8; ++j) o1[j] = tile[tc + 8 + j][d];
        *reinterpret_cast<f16x8*>(dst) = o0;
        *reinterpret_cast<f16x8*>(dst + 8) = o1;
    }
}

// ---------------- Flash attention v6: v4 structure + triple-buffer + counted vmcnt ----------------
// R0 post-mortem: occupancy is NOT the limiter (8-wave split raised occupancy 26->60% and
// REGRESSED 134->195us; MFMA cycles conserved). The stall is the per-iteration vmcnt(0)
// drain implied by __syncthreads before s_barrier: staged loads issued at iter-top must
// fully land before ANY wave crosses, exposing L2/HBM latency x 12-wave straggler.
// Fix (T3/T4): triple-buffered K/V, stage tile t+2 in iter t, and replace __syncthreads
// with {s_waitcnt vmcnt(4); s_barrier} so the freshest 4 loads stay in flight across the
// barrier. vmcnt never drains to 0 in steady state. Hazards: buf[(t+2)%3] was last read
// in iter t-1, fenced by that iter's barrier before the stage issues; FIFO vmcnt ordering
// guarantees stage(t+1) landed when vmcnt<=4.
__global__ __launch_bounds__(256, 3) void k_attn(const half_t* __restrict__ qkv, const half_t* __restrict__ Vt,
                                                 half_t* __restrict__ Y) {
    __shared__ half_t Kb[3][64 * 64];   // [key][d=64], chunk-swizzled (chunk ^= row&7)
    __shared__ half_t Vb[3][64 * 64];   // [d][t=64], chunk-swizzled
    const int tid = threadIdx.x, lane = tid & 63, w = tid >> 6;
    const int lr = lane & 15, g = lane >> 4;
    const int qt = blockIdx.x, bh = blockIdx.y;
    const int b = bh / NH, h = bh - b * NH;
    const half_t* Qp = qkv + (size_t)b * NT * NQKV + h * ND;        // q cols
    const half_t* Kp = Qp + NC;                                     // k cols
    const half_t* Vbase = Vt + (size_t)bh * ND * NT;                // V^T [d][t]
    const int q0 = qt * 128 + w * 32;

    // staging geometry: 256 threads x 16B = 4KB per instr = 32 rows of 128B; 2 instrs per 8KB tile
    const int sr = tid >> 3;                                   // row 0..31 (instr0), +32 (instr1)
    const int colh = (((tid & 7) << 3)) ^ ((sr & 7) << 3);     // swizzled source col (halfs)
    const int wub = (tid & ~63) * 16;                          // wave-uniform LDS byte base

    // Q fragments (B-operand: col=lr=q), 2 q-frags x 2 d-halves, pre-scaled by 1/sqrt(D)*log2(e)
    f16x8 aq[2][2];
    const half_t cch = (half_t)(0.125f * 1.4426950408889634f);
#pragma unroll
    for (int qf = 0; qf < 2; ++qf)
#pragma unroll
        for (int dh = 0; dh < 2; ++dh) {
            aq[qf][dh] = *reinterpret_cast<const f16x8*>(&Qp[(size_t)(q0 + qf * 16 + lr) * NQKV + dh * 32 + g * 8]);
#pragma unroll
            for (int j = 0; j < 8; ++j) aq[qf][dh][j] = aq[qf][dh][j] * cch;
        }

    // swizzled K-read columns (b128): row = st*16+lr, chunk ^= (lr&7)
    const int swk = (lr & 7) << 3;
    const int cA = (g * 8) ^ swk;          // d-chunk 0
    const int cB = (32 + g * 8) ^ swk;     // d-chunk 1
    // swizzled V-read columns (b64 pairs): units at keys 32ks+g*4 and +16
    const int psw = lr & 7;
    const int goff = (g & 1) << 2;
    const int vc[2][2] = { { (((g >> 1) + 0) ^ psw) * 8 + goff, (((g >> 1) + 2) ^ psw) * 8 + goff },
                           { (((g >> 1) + 4) ^ psw) * 8 + goff, (((g >> 1) + 6) ^ psw) * 8 + goff } };

    f32x4 y[2][4];
#pragma unroll
    for (int qf = 0; qf < 2; ++qf)
#pragma unroll
        for (int df = 0; df < 4; ++df) y[qf][df] = (f32x4){0.f, 0.f, 0.f, 0.f};
    float l_[2] = {0.f, 0.f};

    auto stagebuf = [&](int buf, const half_t* Ks, const half_t* Vs) {
        char* kdst = (char*)&Kb[buf][0] + wub;
        char* vdst = (char*)&Vb[buf][0] + wub;
        load_lds16(Ks, kdst);
        load_lds16(Ks + (size_t)32 * NQKV, kdst + 4096);
        load_lds16(Vs, vdst);
        load_lds16(Vs + (size_t)32 * NT, vdst + 4096);
    };

    const half_t* ksrc = Kp + (size_t)sr * NQKV + colh;
    const half_t* vsrc = Vbase + (size_t)sr * NT + colh;
    stagebuf(0, ksrc, vsrc);                                    // tile 0: 4 loads
    stagebuf(1, ksrc + (size_t)64 * NQKV, vsrc + 64);           // tile 1: 4 loads
    ksrc += (size_t)128 * NQKV;
    vsrc += 128;

    // tile 0 landed (4 oldest done), tile 1 stays in flight
    asm volatile("s_waitcnt vmcnt(4)" ::: "memory");
    __builtin_amdgcn_sched_barrier(0);
    __builtin_amdgcn_s_barrier();
    __builtin_amdgcn_sched_barrier(0);

    int cur = 0, nxt = 2;

    for (int t = 0; t < NT / 64; ++t) {
        if (t + 2 < NT / 64) {                                  // stage tile t+2
            stagebuf(nxt, ksrc, vsrc);
            ksrc += (size_t)64 * NQKV;
            vsrc += 64;
            nxt = (nxt == 2) ? 0 : nxt + 1;
        }

        // ---- QK^T (swapped): s[qf][st][i] = S[key=st*16+g*4+i][q=q0+qf*16+lr] ----
        f32x4 s[2][4];
#pragma unroll
        for (int st = 0; st < 4; ++st) { s[0][st] = (f32x4){0.f,0.f,0.f,0.f}; s[1][st] = (f32x4){0.f,0.f,0.f,0.f}; }
        const half_t* Kc = &Kb[cur][0];
        __builtin_amdgcn_s_setprio(1);
#pragma unroll
        for (int st = 0; st < 4; ++st) {
            f16x8 bk0 = *reinterpret_cast<const f16x8*>(&Kc[(st * 16 + lr) * 64 + cA]);
            s[0][st] = MFMA16(bk0, aq[0][0], s[0][st]);
            s[1][st] = MFMA16(bk0, aq[1][0], s[1][st]);
            f16x8 bk1 = *reinterpret_cast<const f16x8*>(&Kc[(st * 16 + lr) * 64 + cB]);
            s[0][st] = MFMA16(bk1, aq[0][1], s[0][st]);
            s[1][st] = MFMA16(bk1, aq[1][1], s[1][st]);
        }
        __builtin_amdgcn_s_setprio(0);

        // ---- no-max softmax + lane-local pack: pb[qf][ks] = packed p[2ks..2ks+1][0..3] ----
        f16x8 pb[2][2];
#pragma unroll
        for (int qf = 0; qf < 2; ++qf) {
            float ps = 0.f;
#pragma unroll
            for (int ks = 0; ks < 2; ++ks) {
                union { f16x8 v; fp16x2 h[4]; } u;
#pragma unroll
                for (int hs = 0; hs < 2; ++hs) {   // hs: which st of this ks-pair
                    const int st = 2 * ks + hs;
                    const float p0 = __builtin_amdgcn_exp2f(s[qf][st][0]);
                    const float p1 = __builtin_amdgcn_exp2f(s[qf][st][1]);
                    const float p2 = __builtin_amdgcn_exp2f(s[qf][st][2]);
                    const float p3 = __builtin_amdgcn_exp2f(s[qf][st][3]);
                    u.h[2 * hs]     = __builtin_amdgcn_cvt_pkrtz(p0, p1);
                    u.h[2 * hs + 1] = __builtin_amdgcn_cvt_pkrtz(p2, p3);
                    ps += (p0 + p1) + (p2 + p3);
                }
                pb[qf][ks] = u.v;
            }
            l_[qf] += ps;
        }

        // ---- PV: A = V^T rows (d=df*16+lr, k-slots per key-permutation), B = pb (register) ----
        const half_t* Vc = &Vb[cur][0];
        __builtin_amdgcn_s_setprio(1);
#pragma unroll
        for (int ks = 0; ks < 2; ++ks)
#pragma unroll
            for (int df = 0; df < 4; ++df) {
                const half_t* vrow = &Vc[(df * 16 + lr) * 64];
                union { f16x8 v; f16x4 q[2]; } va;
                va.q[0] = *reinterpret_cast<const f16x4*>(vrow + vc[ks][0]);
                va.q[1] = *reinterpret_cast<const f16x4*>(vrow + vc[ks][1]);
                y[0][df] = MFMA16(va.v, pb[0][ks], y[0][df]);
                y[1][df] = MFMA16(va.v, pb[1][ks], y[1][df]);
            }
        __builtin_amdgcn_s_setprio(0);

        // counted-vmcnt barrier: tile t+1 landed (4 oldest done); tile t+2 stays in flight.
        // Also fences all waves' reads of buf[cur] before iter t+1 overwrites buf[(t+3)%3].
        if (t < NT / 64 - 1) {
            if (t + 2 < NT / 64) { asm volatile("s_waitcnt vmcnt(4)" ::: "memory"); }
            else                 { asm volatile("s_waitcnt vmcnt(0)" ::: "memory"); }
            __builtin_amdgcn_sched_barrier(0);
            __builtin_amdgcn_s_barrier();
            __builtin_amdgcn_sched_barrier(0);
        }
        cur = (cur == 2) ? 0 : cur + 1;
    }

    // l reduce across the 4 g-groups (keys partitioned by g,st), then store
#pragma unroll
    for (int qf = 0; qf < 2; ++qf) {
        float l = l_[qf];
        l += __shfl_xor(l, 16);
        l += __shfl_xor(l, 32);
        const float rl = 1.f / l;
        half_t* Yp = Y + (size_t)(b * NT + q0 + qf * 16 + lr) * NC + h * ND + g * 4;
#pragma unroll
        for (int df = 0; df < 4; ++df) {
            union { f16x4 v; fp16x2 hh[2]; } o;
            o.hh[0] = __builtin_amdgcn_cvt_pkrtz(y[qf][df][0] * rl, y[qf][df][1] * rl);
            o.hh[1] = __builtin_amdgcn_cvt_pkrtz(y[qf][df][2] * rl, y[qf][df][3] * rl);
            *reinterpret_cast<f16x4*>(Yp + df * 16) = o.v;
        }
    }
}

extern "C" void kernel_launch(void* const* d_in, const int* in_sizes, int n_in,
                              void* d_out, int out_size, void* d_ws, size_t ws_size,
                              hipStream_t stream) {
    const float* x  = (const float*)d_in[0];
    const float* Wa = (const float*)d_in[1];
    const float* ba = (const float*)d_in[2];
    const float* Wp = (const float*)d_in[3];
    const float* bp = (const float*)d_in[4];
    float* out = (float*)d_out;

    char* ws = (char*)d_ws;
    half_t* xh   = (half_t*)ws; ws += (size_t)NBT * NC * 2;
    half_t* Wat  = (half_t*)ws; ws += (size_t)NQKV * NC * 2;
    half_t* Wpt  = (half_t*)ws; ws += (size_t)NC * NC * 2;
    half_t* qkvh = (half_t*)ws; ws += (size_t)NBT * NQKV * 2;
    half_t* vt   = (half_t*)ws; ws += (size_t)NB * NH * ND * NT * 2;
    half_t* yh   = (half_t*)ws; ws += (size_t)NBT * NC * 2;

    k_pack<<<(NBT * NC / 4 + 255) / 256, 256, 0, stream>>>(x, xh, NBT * NC / 4);
    k_packT<<<(NQKV * NC + 255) / 256, 256, 0, stream>>>(Wa, Wat, NQKV, NC);
    k_packT<<<(NC * NC + 255) / 256, 256, 0, stream>>>(Wp, Wpt, NC, NC);
    k_gemm<0><<<dim3(NBT / 128, NQKV / 128), 256, 0, stream>>>(xh, Wat, ba, qkvh, NQKV);
    k_vt<<<dim3(NT / 64, NB * NH), 256, 0, stream>>>(qkvh, vt);
    k_attn<<<dim3(NT / 128, NB * NH), 256, 0, stream>>>(qkvh, vt, yh);
    k_gemm<1><<<dim3(NBT / 128, NC / 128), 256, 0, stream>>>(yh, Wpt, bp, out, NC);
}